// Round 2
// baseline (694.004 us; speedup 1.0000x reference)
//
#include <hip/hip_runtime.h>

// ---------------- bucketed CSR build ----------------
// Buckets of 64 dst nodes. Packed edge entry: (local_dst<<17) | src  (needs n <= 131072).

#define PSHIFT 6
#define PNODES 64
#define BCAP   1408   // mean 1024 edges/bucket, sd ~32 -> 12 sigma headroom

__global__ __launch_bounds__(256) void k_binA(const int* __restrict__ src,
                                              const int* __restrict__ dst,
                                              int* __restrict__ bcnt,
                                              unsigned int* __restrict__ bdata, int E) {
    int i = blockIdx.x * 256 + threadIdx.x;
    if (i >= E) return;
    int d = dst[i], s = src[i];
    int b = d >> PSHIFT;
    int local = d & (PNODES - 1);
    int pos = atomicAdd(&bcnt[b], 1);
    if (pos < BCAP) bdata[(size_t)b * BCAP + pos] = ((unsigned)local << 17) | (unsigned)s;
}

// single-block exclusive scan over bucket counts -> bucket bases; also writes offsets[n]
__global__ __launch_bounds__(256) void k_bscan(const int* __restrict__ bcnt,
                                               int* __restrict__ bbase,
                                               int* __restrict__ offsets,
                                               int B, int n) {
    __shared__ int sd[256];
    int K = (B + 255) / 256;
    int t = threadIdx.x;
    int s = 0;
    for (int j = 0; j < K; j++) {
        int b = t * K + j;
        if (b < B) s += min(bcnt[b], BCAP);
    }
    sd[t] = s;
    __syncthreads();
    int acc = s;
    for (int off = 1; off < 256; off <<= 1) {
        int v = (t >= off) ? sd[t - off] : 0;
        __syncthreads();
        acc += v;
        sd[t] = acc;
        __syncthreads();
    }
    int run = acc - s;  // exclusive prefix
    for (int j = 0; j < K; j++) {
        int b = t * K + j;
        if (b < B) { bbase[b] = run; run += min(bcnt[b], BCAP); }
    }
    if (t == 255) offsets[n] = run;  // == E (no bucket overflow in practice)
}

// one block per bucket: LDS histogram -> deg/norm/offsets, then scatter cols
__global__ __launch_bounds__(256) void k_binB(const unsigned int* __restrict__ bdata,
                                              const int* __restrict__ bcnt,
                                              const int* __restrict__ bbase,
                                              int* __restrict__ offsets,
                                              float* __restrict__ norm,
                                              int* __restrict__ cols, int n) {
    __shared__ int hist[PNODES];
    __shared__ int lofs[PNODES];
    __shared__ int cur[PNODES];
    int b = blockIdx.x;
    int t = threadIdx.x;
    int cnt = min(bcnt[b], BCAP);
    int base = bbase[b];
    const unsigned int* bd = bdata + (size_t)b * BCAP;

    if (t < PNODES) hist[t] = 0;
    __syncthreads();
    for (int e = t; e < cnt; e += 256) atomicAdd(&hist[bd[e] >> 17], 1);
    __syncthreads();
    // Hillis-Steele inclusive scan over 64 entries (all threads hit barriers)
    if (t < PNODES) lofs[t] = hist[t];
    __syncthreads();
    for (int off = 1; off < PNODES; off <<= 1) {
        int v = 0;
        if (t < PNODES && t >= off) v = lofs[t - off];
        __syncthreads();
        if (t < PNODES) lofs[t] += v;
        __syncthreads();
    }
    if (t < PNODES) {
        int excl = lofs[t] - hist[t];
        cur[t] = excl;
        int node = (b << PSHIFT) + t;
        if (node < n) {
            offsets[node] = base + excl;
            norm[node] = 1.0f / ((float)hist[t] + 1.0f);
        }
    }
    __syncthreads();
    for (int e = t; e < cnt; e += 256) {
        unsigned v = bd[e];
        int local = v >> 17;
        int s = (int)(v & 0x1FFFF);
        int r = atomicAdd(&cur[local], 1);
        cols[base + r] = s;  // writes land in a ~4KB contiguous window
    }
}

// ---------------- aggregation: t[v] = (h[v] + sum_in h[c]) * norm[v] ----------------
// 128-wide rows: 32 lanes/node, float4/lane; 8 nodes per 256-thread block.

__global__ __launch_bounds__(256) void k_aggregate(const float* __restrict__ h,
                                                   const int* __restrict__ offs,
                                                   const int* __restrict__ cols,
                                                   const float* __restrict__ norm,
                                                   float* __restrict__ t, int n) {
    int node = blockIdx.x * 8 + (threadIdx.x >> 5);
    if (node >= n) return;
    int lane = threadIdx.x & 31;

    float4 acc = ((const float4*)(h + (size_t)node * 128))[lane];
    int p = offs[node], e = offs[node + 1];
    for (; p + 2 <= e; p += 2) {
        int c0 = cols[p], c1 = cols[p + 1];
        float4 a = ((const float4*)(h + (size_t)c0 * 128))[lane];
        float4 b = ((const float4*)(h + (size_t)c1 * 128))[lane];
        acc.x += a.x + b.x; acc.y += a.y + b.y; acc.z += a.z + b.z; acc.w += a.w + b.w;
    }
    if (p < e) {
        int c0 = cols[p];
        float4 a = ((const float4*)(h + (size_t)c0 * 128))[lane];
        acc.x += a.x; acc.y += a.y; acc.z += a.z; acc.w += a.w;
    }
    float nm = norm[node];
    acc.x *= nm; acc.y *= nm; acc.z *= nm; acc.w *= nm;
    ((float4*)(t + (size_t)node * 128))[lane] = acc;
}

// 64-wide rows + bias (layer-3 transform-first): out[v] = (g[v]+sum g[c])*norm[v] + b
__global__ __launch_bounds__(256) void k_aggregate64b(const float* __restrict__ g,
                                                      const int* __restrict__ offs,
                                                      const int* __restrict__ cols,
                                                      const float* __restrict__ norm,
                                                      const float* __restrict__ bias,
                                                      float* __restrict__ out, int n) {
    int node = blockIdx.x * 16 + (threadIdx.x >> 4);
    if (node >= n) return;
    int lane = threadIdx.x & 15;

    float4 acc = ((const float4*)(g + (size_t)node * 64))[lane];
    int p = offs[node], e = offs[node + 1];
    for (; p + 2 <= e; p += 2) {
        int c0 = cols[p], c1 = cols[p + 1];
        float4 a = ((const float4*)(g + (size_t)c0 * 64))[lane];
        float4 b = ((const float4*)(g + (size_t)c1 * 64))[lane];
        acc.x += a.x + b.x; acc.y += a.y + b.y; acc.z += a.z + b.z; acc.w += a.w + b.w;
    }
    if (p < e) {
        int c0 = cols[p];
        float4 a = ((const float4*)(g + (size_t)c0 * 64))[lane];
        acc.x += a.x; acc.y += a.y; acc.z += a.z; acc.w += a.w;
    }
    float nm = norm[node];
    float4 bb = ((const float4*)bias)[lane];
    acc.x = acc.x * nm + bb.x; acc.y = acc.y * nm + bb.y;
    acc.z = acc.z * nm + bb.z; acc.w = acc.w * nm + bb.w;
    ((float4*)(out + (size_t)node * 64))[lane] = acc;
}

// ---------------- GEMM: out[m][j] = act(dot(A[m][:128], W[j][:128]) [+ b[j]]) ----------------

template <int KOUT, bool RELU, bool BIAS>
__global__ __launch_bounds__(256) void k_gemm(const float* __restrict__ A,
                                              const float* __restrict__ W,
                                              const float* __restrict__ bias,
                                              float* __restrict__ out, int n) {
    constexpr int TN = (KOUT == 128) ? 8 : 4;
    __shared__ __align__(16) float tA[32][128];
    __shared__ __align__(16) float WT[32][KOUT];

    int tid  = threadIdx.x;
    int trow = tid >> 4;
    int tcol = tid & 15;
    int m0   = blockIdx.x * 128;
    int mt   = trow * 8;
    int j0   = tcol * TN;
    int sw   = ((j0 >> 5) & 3) << 2;

    float acc[8][TN];
#pragma unroll
    for (int i = 0; i < 8; i++)
#pragma unroll
        for (int j = 0; j < TN; j++) acc[i][j] = 0.f;

    for (int k0 = 0; k0 < 128; k0 += 32) {
        __syncthreads();
#pragma unroll
        for (int j = 0; j < 4; j++) {
            int idx = tid * 4 + j;
            int q = idx & 7, m = idx >> 3;
            int gm = m0 + m;
            float4 v = make_float4(0.f, 0.f, 0.f, 0.f);
            if (gm < n) v = *(const float4*)(A + (size_t)gm * 128 + k0 + q * 4);
            tA[q * 4 + 0][m] = v.x;
            tA[q * 4 + 1][m] = v.y;
            tA[q * 4 + 2][m] = v.z;
            tA[q * 4 + 3][m] = v.w;
        }
#pragma unroll
        for (int j = 0; j < KOUT / 32; j++) {
            int idx = tid * (KOUT / 32) + j;
            int q = idx & 7, jj = idx >> 3;
            float4 v = *(const float4*)(W + (size_t)jj * 128 + k0 + q * 4);
            int js = jj ^ (((jj >> 5) & 3) << 2);
            WT[q * 4 + 0][js] = v.x;
            WT[q * 4 + 1][js] = v.y;
            WT[q * 4 + 2][js] = v.z;
            WT[q * 4 + 3][js] = v.w;
        }
        __syncthreads();

#pragma unroll
        for (int k = 0; k < 32; k++) {
            float a[8], b[TN];
            *(float4*)&a[0] = *(const float4*)&tA[k][mt];
            *(float4*)&a[4] = *(const float4*)&tA[k][mt + 4];
            *(float4*)&b[0] = *(const float4*)&WT[k][j0 ^ sw];
            if constexpr (TN == 8)
                *(float4*)&b[4] = *(const float4*)&WT[k][(j0 + 4) ^ sw];
#pragma unroll
            for (int i = 0; i < 8; i++)
#pragma unroll
                for (int j = 0; j < TN; j++) acc[i][j] = fmaf(a[i], b[j], acc[i][j]);
        }
    }

    float bj[TN];
#pragma unroll
    for (int j = 0; j < TN; j++) bj[j] = BIAS ? bias[j0 + j] : 0.f;

#pragma unroll
    for (int i = 0; i < 8; i++) {
        int gm = m0 + mt + i;
        if (gm < n) {
            float o[TN];
#pragma unroll
            for (int j = 0; j < TN; j++) {
                float v = acc[i][j] + bj[j];
                if (RELU) v = fmaxf(v, 0.f);
                o[j] = v;
            }
            float* op = out + (size_t)gm * KOUT + j0;
            *(float4*)&op[0] = *(const float4*)&o[0];
            if constexpr (TN == 8) *(float4*)&op[4] = *(const float4*)&o[4];
        }
    }
}

// ---------------- launch ----------------

extern "C" void kernel_launch(void* const* d_in, const int* in_sizes, int n_in,
                              void* d_out, int out_size, void* d_ws, size_t ws_size,
                              hipStream_t stream) {
    const float* x  = (const float*)d_in[0];
    const int*  src = (const int*)d_in[1];
    const int*  dst = (const int*)d_in[2];
    const float* W1 = (const float*)d_in[3];
    const float* b1 = (const float*)d_in[4];
    const float* W2 = (const float*)d_in[5];
    const float* b2 = (const float*)d_in[6];
    const float* W3 = (const float*)d_in[7];
    const float* b3 = (const float*)d_in[8];
    float* out = (float*)d_out;

    int n = in_sizes[0] / 128;
    int E = in_sizes[1];
    int B = (n + PNODES - 1) >> PSHIFT;

    char* ws = (char*)d_ws;
    size_t off = 0;
    auto alloc = [&](size_t bytes) -> char* {
        char* p = ws + off;
        off += (bytes + 255) & ~(size_t)255;
        return p;
    };
    int*   bcnt    = (int*)alloc((size_t)B * 4);
    int*   bbase   = (int*)alloc((size_t)B * 4);
    int*   offsets = (int*)alloc(((size_t)n + 1) * 4);
    float* norm    = (float*)alloc((size_t)n * 4);
    int*   cols    = (int*)alloc((size_t)E * 4);
    float* tbuf    = (float*)alloc((size_t)n * 128 * 4);
    float* hbuf    = (float*)alloc((size_t)n * 128 * 4);
    // bdata aliases tbuf: CSR build finishes before tbuf's first use
    unsigned int* bdata = (unsigned int*)tbuf;  // B*BCAP*4 = 8.8 MB << 51.2 MB

    hipMemsetAsync(bcnt, 0, (size_t)B * 4, stream);

    int nblkE = (E + 255) / 256;
    k_binA<<<nblkE, 256, 0, stream>>>(src, dst, bcnt, bdata, E);
    k_bscan<<<1, 256, 0, stream>>>(bcnt, bbase, offsets, B, n);
    k_binB<<<B, 256, 0, stream>>>(bdata, bcnt, bbase, offsets, norm, cols, n);

    int nblkA  = (n + 7) / 8;
    int nblkA6 = (n + 15) / 16;
    int nblkG  = (n + 127) / 128;

    // layer 1: x -> t -> h
    k_aggregate<<<nblkA, 256, 0, stream>>>(x, offsets, cols, norm, tbuf, n);
    k_gemm<128, true, true><<<nblkG, 256, 0, stream>>>(tbuf, W1, b1, hbuf, n);
    // layer 2: h -> t -> h
    k_aggregate<<<nblkA, 256, 0, stream>>>(hbuf, offsets, cols, norm, tbuf, n);
    k_gemm<128, true, true><<<nblkG, 256, 0, stream>>>(tbuf, W2, b2, hbuf, n);
    // layer 3 (transform-first): g = h @ W3^T ; out = (g + sum g)*norm + b3
    k_gemm<64, false, false><<<nblkG, 256, 0, stream>>>(hbuf, W3, b3, tbuf, n);
    k_aggregate64b<<<nblkA6, 256, 0, stream>>>(tbuf, offsets, cols, norm, b3, out, n);
}

// Round 3
// 655.352 us; speedup vs baseline: 1.0590x; 1.0590x over previous
//
#include <hip/hip_runtime.h>

// ---------------- CSR build: block-private two-pass counting sort ----------------
// Coarse buckets of 64 dst nodes; packed entry (local_dst<<17)|src (needs n <= 131072).

#define PSHIFT 6
#define PNODES 64
#define BMAX   2048   // max coarse buckets (n <= 131072)
#define NBLK   64     // edge-chunk blocks

// pass 1: per-chunk LDS histogram -> histT[bucket][block]
__global__ __launch_bounds__(512) void k_hist(const int* __restrict__ dst, int E, int chunk,
                                              int B, int* __restrict__ histT) {
    __shared__ int hist[BMAX];
    int blk = blockIdx.x, t = threadIdx.x;
    for (int k = t; k < B; k += 512) hist[k] = 0;
    __syncthreads();
    int lo = blk * chunk, hi = min(lo + chunk, E);
    for (int i = lo + t; i < hi; i += 512) atomicAdd(&hist[dst[i] >> PSHIFT], 1);
    __syncthreads();
    for (int k = t; k < B; k += 512) histT[k * NBLK + blk] = hist[k];
}

// exclusive scan of histT (bucket-major) in place; scanned[k][b] = start slot of
// (bucket k, block b). Also bucket bases and offsets[n].
__global__ __launch_bounds__(1024) void k_scanE(int* __restrict__ histT, int total,
                                                int* __restrict__ bbase, int B,
                                                int* __restrict__ offsets, int n, int E) {
    __shared__ int sd[1024];
    int t = threadIdx.x;
    int K = (total + 1023) / 1024;
    int lo = t * K, hi = min(lo + K, total);
    int s = 0;
    for (int i = lo; i < hi; i++) s += histT[i];
    sd[t] = s;
    __syncthreads();
    int acc = s;
    for (int off = 1; off < 1024; off <<= 1) {
        int v = (t >= off) ? sd[t - off] : 0;
        __syncthreads();
        acc += v;
        sd[t] = acc;
        __syncthreads();
    }
    int run = acc - s;  // exclusive prefix of this thread's range
    for (int i = lo; i < hi; i++) {
        int v = histT[i];
        histT[i] = run;
        if ((i & (NBLK - 1)) == 0) bbase[i / NBLK] = run;
        run += v;
    }
    if (t == 0) { bbase[B] = E; offsets[n] = E; }
}

// pass 2: re-read chunk, place entries into block-private runs (coalesced-ish writes)
__global__ __launch_bounds__(512) void k_place(const int* __restrict__ src,
                                               const int* __restrict__ dst,
                                               const int* __restrict__ histT,
                                               int E, int chunk, int B,
                                               unsigned int* __restrict__ ebuf) {
    __shared__ int cur[BMAX];
    int blk = blockIdx.x, t = threadIdx.x;
    for (int k = t; k < B; k += 512) cur[k] = histT[k * NBLK + blk];
    __syncthreads();
    int lo = blk * chunk, hi = min(lo + chunk, E);
    for (int i = lo + t; i < hi; i += 512) {
        int d = dst[i], s = src[i];
        int k = d >> PSHIFT;
        int pos = atomicAdd(&cur[k], 1);
        ebuf[pos] = ((unsigned)(d & (PNODES - 1)) << 17) | (unsigned)s;
    }
}

// one block per bucket: LDS histogram -> deg/norm/offsets, then scatter cols
// (writes land in a contiguous ~4KB window)
__global__ __launch_bounds__(256) void k_binB(const unsigned int* __restrict__ ebuf,
                                              const int* __restrict__ bbase,
                                              int* __restrict__ offsets,
                                              float* __restrict__ norm,
                                              int* __restrict__ cols, int n) {
    __shared__ int hist[PNODES];
    __shared__ int lofs[PNODES];
    __shared__ int cur[PNODES];
    int b = blockIdx.x;
    int t = threadIdx.x;
    int base = bbase[b];
    int cnt = bbase[b + 1] - base;
    const unsigned int* bd = ebuf + base;

    if (t < PNODES) hist[t] = 0;
    __syncthreads();
    for (int e = t; e < cnt; e += 256) atomicAdd(&hist[bd[e] >> 17], 1);
    __syncthreads();
    if (t < PNODES) lofs[t] = hist[t];
    __syncthreads();
    for (int off = 1; off < PNODES; off <<= 1) {
        int v = 0;
        if (t < PNODES && t >= off) v = lofs[t - off];
        __syncthreads();
        if (t < PNODES) lofs[t] += v;
        __syncthreads();
    }
    if (t < PNODES) {
        int excl = lofs[t] - hist[t];
        cur[t] = excl;
        int node = (b << PSHIFT) + t;
        if (node < n) {
            offsets[node] = base + excl;
            norm[node] = 1.0f / ((float)hist[t] + 1.0f);
        }
    }
    __syncthreads();
    for (int e = t; e < cnt; e += 256) {
        unsigned v = bd[e];
        int local = v >> 17;
        int s = (int)(v & 0x1FFFF);
        int r = atomicAdd(&cur[local], 1);
        cols[base + r] = s;
    }
}

// ---------------- aggregation: t[v] = (h[v] + sum_in h[c]) * norm[v] ----------------

__global__ __launch_bounds__(256) void k_aggregate(const float* __restrict__ h,
                                                   const int* __restrict__ offs,
                                                   const int* __restrict__ cols,
                                                   const float* __restrict__ norm,
                                                   float* __restrict__ t, int n) {
    int node = blockIdx.x * 8 + (threadIdx.x >> 5);
    if (node >= n) return;
    int lane = threadIdx.x & 31;

    float4 acc = ((const float4*)(h + (size_t)node * 128))[lane];
    int p = offs[node], e = offs[node + 1];
    for (; p + 2 <= e; p += 2) {
        int c0 = cols[p], c1 = cols[p + 1];
        float4 a = ((const float4*)(h + (size_t)c0 * 128))[lane];
        float4 b = ((const float4*)(h + (size_t)c1 * 128))[lane];
        acc.x += a.x + b.x; acc.y += a.y + b.y; acc.z += a.z + b.z; acc.w += a.w + b.w;
    }
    if (p < e) {
        int c0 = cols[p];
        float4 a = ((const float4*)(h + (size_t)c0 * 128))[lane];
        acc.x += a.x; acc.y += a.y; acc.z += a.z; acc.w += a.w;
    }
    float nm = norm[node];
    acc.x *= nm; acc.y *= nm; acc.z *= nm; acc.w *= nm;
    ((float4*)(t + (size_t)node * 128))[lane] = acc;
}

// 64-wide rows + bias (layer-3 transform-first): out[v] = (g[v]+sum g[c])*norm[v] + b
__global__ __launch_bounds__(256) void k_aggregate64b(const float* __restrict__ g,
                                                      const int* __restrict__ offs,
                                                      const int* __restrict__ cols,
                                                      const float* __restrict__ norm,
                                                      const float* __restrict__ bias,
                                                      float* __restrict__ out, int n) {
    int node = blockIdx.x * 16 + (threadIdx.x >> 4);
    if (node >= n) return;
    int lane = threadIdx.x & 15;

    float4 acc = ((const float4*)(g + (size_t)node * 64))[lane];
    int p = offs[node], e = offs[node + 1];
    for (; p + 2 <= e; p += 2) {
        int c0 = cols[p], c1 = cols[p + 1];
        float4 a = ((const float4*)(g + (size_t)c0 * 64))[lane];
        float4 b = ((const float4*)(g + (size_t)c1 * 64))[lane];
        acc.x += a.x + b.x; acc.y += a.y + b.y; acc.z += a.z + b.z; acc.w += a.w + b.w;
    }
    if (p < e) {
        int c0 = cols[p];
        float4 a = ((const float4*)(g + (size_t)c0 * 64))[lane];
        acc.x += a.x; acc.y += a.y; acc.z += a.z; acc.w += a.w;
    }
    float nm = norm[node];
    float4 bb = ((const float4*)bias)[lane];
    acc.x = acc.x * nm + bb.x; acc.y = acc.y * nm + bb.y;
    acc.z = acc.z * nm + bb.z; acc.w = acc.w * nm + bb.w;
    ((float4*)(out + (size_t)node * 64))[lane] = acc;
}

// ---------------- GEMM: out[m][j] = act(dot(A[m][:128], W[j][:128]) [+ b[j]]) ----------------

template <int KOUT, bool RELU, bool BIAS>
__global__ __launch_bounds__(256) void k_gemm(const float* __restrict__ A,
                                              const float* __restrict__ W,
                                              const float* __restrict__ bias,
                                              float* __restrict__ out, int n) {
    constexpr int TN = (KOUT == 128) ? 8 : 4;
    __shared__ __align__(16) float tA[32][128];
    __shared__ __align__(16) float WT[32][KOUT];

    int tid  = threadIdx.x;
    int trow = tid >> 4;
    int tcol = tid & 15;
    int m0   = blockIdx.x * 128;
    int mt   = trow * 8;
    int j0   = tcol * TN;
    int sw   = ((j0 >> 5) & 3) << 2;

    float acc[8][TN];
#pragma unroll
    for (int i = 0; i < 8; i++)
#pragma unroll
        for (int j = 0; j < TN; j++) acc[i][j] = 0.f;

    for (int k0 = 0; k0 < 128; k0 += 32) {
        __syncthreads();
#pragma unroll
        for (int j = 0; j < 4; j++) {
            int idx = tid * 4 + j;
            int q = idx & 7, m = idx >> 3;
            int gm = m0 + m;
            float4 v = make_float4(0.f, 0.f, 0.f, 0.f);
            if (gm < n) v = *(const float4*)(A + (size_t)gm * 128 + k0 + q * 4);
            tA[q * 4 + 0][m] = v.x;
            tA[q * 4 + 1][m] = v.y;
            tA[q * 4 + 2][m] = v.z;
            tA[q * 4 + 3][m] = v.w;
        }
#pragma unroll
        for (int j = 0; j < KOUT / 32; j++) {
            int idx = tid * (KOUT / 32) + j;
            int q = idx & 7, jj = idx >> 3;
            float4 v = *(const float4*)(W + (size_t)jj * 128 + k0 + q * 4);
            int js = jj ^ (((jj >> 5) & 3) << 2);
            WT[q * 4 + 0][js] = v.x;
            WT[q * 4 + 1][js] = v.y;
            WT[q * 4 + 2][js] = v.z;
            WT[q * 4 + 3][js] = v.w;
        }
        __syncthreads();

#pragma unroll
        for (int k = 0; k < 32; k++) {
            float a[8], b[TN];
            *(float4*)&a[0] = *(const float4*)&tA[k][mt];
            *(float4*)&a[4] = *(const float4*)&tA[k][mt + 4];
            *(float4*)&b[0] = *(const float4*)&WT[k][j0 ^ sw];
            if constexpr (TN == 8)
                *(float4*)&b[4] = *(const float4*)&WT[k][(j0 + 4) ^ sw];
#pragma unroll
            for (int i = 0; i < 8; i++)
#pragma unroll
                for (int j = 0; j < TN; j++) acc[i][j] = fmaf(a[i], b[j], acc[i][j]);
        }
    }

    float bj[TN];
#pragma unroll
    for (int j = 0; j < TN; j++) bj[j] = BIAS ? bias[j0 + j] : 0.f;

#pragma unroll
    for (int i = 0; i < 8; i++) {
        int gm = m0 + mt + i;
        if (gm < n) {
            float o[TN];
#pragma unroll
            for (int j = 0; j < TN; j++) {
                float v = acc[i][j] + bj[j];
                if (RELU) v = fmaxf(v, 0.f);
                o[j] = v;
            }
            float* op = out + (size_t)gm * KOUT + j0;
            *(float4*)&op[0] = *(const float4*)&o[0];
            if constexpr (TN == 8) *(float4*)&op[4] = *(const float4*)&o[4];
        }
    }
}

// ---------------- launch ----------------

extern "C" void kernel_launch(void* const* d_in, const int* in_sizes, int n_in,
                              void* d_out, int out_size, void* d_ws, size_t ws_size,
                              hipStream_t stream) {
    const float* x  = (const float*)d_in[0];
    const int*  src = (const int*)d_in[1];
    const int*  dst = (const int*)d_in[2];
    const float* W1 = (const float*)d_in[3];
    const float* b1 = (const float*)d_in[4];
    const float* W2 = (const float*)d_in[5];
    const float* b2 = (const float*)d_in[6];
    const float* W3 = (const float*)d_in[7];
    const float* b3 = (const float*)d_in[8];
    float* out = (float*)d_out;

    int n = in_sizes[0] / 128;
    int E = in_sizes[1];
    int B = (n + PNODES - 1) >> PSHIFT;
    int total = B * NBLK;
    int chunk = (E + NBLK - 1) / NBLK;

    char* ws = (char*)d_ws;
    size_t off = 0;
    auto alloc = [&](size_t bytes) -> char* {
        char* p = ws + off;
        off += (bytes + 255) & ~(size_t)255;
        return p;
    };
    int*   bbase   = (int*)alloc(((size_t)B + 1) * 4);
    int*   offsets = (int*)alloc(((size_t)n + 1) * 4);
    float* norm    = (float*)alloc((size_t)n * 4);
    int*   cols    = (int*)alloc((size_t)E * 4);
    float* tbuf    = (float*)alloc((size_t)n * 128 * 4);
    float* hbuf    = (float*)alloc((size_t)n * 128 * 4);
    // CSR-build scratch aliases tbuf (dead until layer-1 aggregate output):
    unsigned int* ebuf  = (unsigned int*)tbuf;                     // E*4 = 6.4 MB
    int*          histT = (int*)(tbuf + (size_t)2 * 1024 * 1024);  // at +8 MB, 400 KB

    k_hist <<<NBLK, 512, 0, stream>>>(dst, E, chunk, B, histT);
    k_scanE<<<1, 1024, 0, stream>>>(histT, total, bbase, B, offsets, n, E);
    k_place<<<NBLK, 512, 0, stream>>>(src, dst, histT, E, chunk, B, ebuf);
    k_binB <<<B, 256, 0, stream>>>(ebuf, bbase, offsets, norm, cols, n);

    int nblkA  = (n + 7) / 8;
    int nblkA6 = (n + 15) / 16;
    int nblkG  = (n + 127) / 128;

    // layer 1: x -> t -> h
    k_aggregate<<<nblkA, 256, 0, stream>>>(x, offsets, cols, norm, tbuf, n);
    k_gemm<128, true, true><<<nblkG, 256, 0, stream>>>(tbuf, W1, b1, hbuf, n);
    // layer 2: h -> t -> h
    k_aggregate<<<nblkA, 256, 0, stream>>>(hbuf, offsets, cols, norm, tbuf, n);
    k_gemm<128, true, true><<<nblkG, 256, 0, stream>>>(tbuf, W2, b2, hbuf, n);
    // layer 3 (transform-first): g = h @ W3^T ; out = (g + sum g)*norm + b3
    k_gemm<64, false, false><<<nblkG, 256, 0, stream>>>(hbuf, W3, b3, tbuf, n);
    k_aggregate64b<<<nblkA6, 256, 0, stream>>>(tbuf, offsets, cols, norm, b3, out, n);
}

// Round 4
// 374.367 us; speedup vs baseline: 1.8538x; 1.7506x over previous
//
#include <hip/hip_runtime.h>
#include <hip/hip_fp16.h>

typedef _Float16 half8 __attribute__((ext_vector_type(8)));
typedef _Float16 half4 __attribute__((ext_vector_type(4)));

// ---------------- CSR build: block-private two-pass counting sort ----------------
// Coarse buckets of 64 dst nodes; packed entry (local_dst<<17)|src (needs n <= 131072).

#define PSHIFT 6
#define PNODES 64
#define BMAX   2048
#define NBLK   64

__global__ __launch_bounds__(512) void k_hist(const int* __restrict__ dst, int E, int chunk,
                                              int B, int* __restrict__ histT) {
    __shared__ int hist[BMAX];
    int blk = blockIdx.x, t = threadIdx.x;
    for (int k = t; k < B; k += 512) hist[k] = 0;
    __syncthreads();
    int lo = blk * chunk, hi = min(lo + chunk, E);
    for (int i = lo + t; i < hi; i += 512) atomicAdd(&hist[dst[i] >> PSHIFT], 1);
    __syncthreads();
    for (int k = t; k < B; k += 512) histT[k * NBLK + blk] = hist[k];
}

// ---- parallel exclusive scan of histT (flat, bucket-major), 3 phases ----

__global__ __launch_bounds__(256) void k_scanA(const int* __restrict__ histT, int total,
                                               int* __restrict__ psum) {
    __shared__ int sd[256];
    int t = threadIdx.x;
    int base = blockIdx.x * 1024 + t * 4;
    int s = 0;
    if (base + 3 < total) {
        int4 v = *(const int4*)(histT + base);
        s = v.x + v.y + v.z + v.w;
    } else {
        for (int j = 0; j < 4; j++) if (base + j < total) s += histT[base + j];
    }
    sd[t] = s;
    __syncthreads();
    for (int off = 128; off > 0; off >>= 1) {
        if (t < off) sd[t] += sd[t + off];
        __syncthreads();
    }
    if (t == 0) psum[blockIdx.x] = sd[0];
}

__global__ __launch_bounds__(128) void k_scanB(const int* __restrict__ psum, int G,
                                               int* __restrict__ pbase,
                                               int* __restrict__ bbase, int B,
                                               int* __restrict__ offsets, int n, int E) {
    __shared__ int sd[128];
    int t = threadIdx.x;
    int v = (t < G) ? psum[t] : 0;
    sd[t] = v;
    __syncthreads();
    int acc = v;
    for (int off = 1; off < 128; off <<= 1) {
        int u = (t >= off) ? sd[t - off] : 0;
        __syncthreads();
        acc += u;
        sd[t] = acc;
        __syncthreads();
    }
    if (t < G) pbase[t] = acc - v;
    if (t == 0) { bbase[B] = E; offsets[n] = E; }
}

__global__ __launch_bounds__(256) void k_scanC(int* __restrict__ histT, int total,
                                               const int* __restrict__ pbase,
                                               int* __restrict__ bbase) {
    __shared__ int sd[256];
    int t = threadIdx.x;
    int base = blockIdx.x * 1024 + t * 4;
    int v[4];
    int s = 0;
    bool full = (base + 3 < total);
    if (full) {
        int4 q = *(const int4*)(histT + base);
        v[0] = q.x; v[1] = q.y; v[2] = q.z; v[3] = q.w;
        s = q.x + q.y + q.z + q.w;
    } else {
#pragma unroll
        for (int j = 0; j < 4; j++) { v[j] = (base + j < total) ? histT[base + j] : 0; s += v[j]; }
    }
    sd[t] = s;
    __syncthreads();
    int acc = s;
    for (int off = 1; off < 256; off <<= 1) {
        int u = (t >= off) ? sd[t - off] : 0;
        __syncthreads();
        acc += u;
        sd[t] = acc;
        __syncthreads();
    }
    int run = pbase[blockIdx.x] + (acc - s);
    int o[4];
#pragma unroll
    for (int j = 0; j < 4; j++) { o[j] = run; run += v[j]; }
    if (full) *(int4*)(histT + base) = make_int4(o[0], o[1], o[2], o[3]);
    else { for (int j = 0; j < 4; j++) if (base + j < total) histT[base + j] = o[j]; }
    if ((base & 63) == 0 && base < total) bbase[base >> 6] = o[0];  // flat idx k*NBLK
}

// pass 2: place entries into block-private runs
__global__ __launch_bounds__(512) void k_place(const int* __restrict__ src,
                                               const int* __restrict__ dst,
                                               const int* __restrict__ histT,
                                               int E, int chunk, int B,
                                               unsigned int* __restrict__ ebuf) {
    __shared__ int cur[BMAX];
    int blk = blockIdx.x, t = threadIdx.x;
    for (int k = t; k < B; k += 512) cur[k] = histT[k * NBLK + blk];
    __syncthreads();
    int lo = blk * chunk, hi = min(lo + chunk, E);
    for (int i = lo + t; i < hi; i += 512) {
        int d = dst[i], s = src[i];
        int k = d >> PSHIFT;
        int pos = atomicAdd(&cur[k], 1);
        ebuf[pos] = ((unsigned)(d & (PNODES - 1)) << 17) | (unsigned)s;
    }
}

__global__ __launch_bounds__(256) void k_binB(const unsigned int* __restrict__ ebuf,
                                              const int* __restrict__ bbase,
                                              int* __restrict__ offsets,
                                              float* __restrict__ norm,
                                              int* __restrict__ cols, int n) {
    __shared__ int hist[PNODES];
    __shared__ int lofs[PNODES];
    __shared__ int cur[PNODES];
    int b = blockIdx.x;
    int t = threadIdx.x;
    int base = bbase[b];
    int cnt = bbase[b + 1] - base;
    const unsigned int* bd = ebuf + base;

    if (t < PNODES) hist[t] = 0;
    __syncthreads();
    for (int e = t; e < cnt; e += 256) atomicAdd(&hist[bd[e] >> 17], 1);
    __syncthreads();
    if (t < PNODES) lofs[t] = hist[t];
    __syncthreads();
    for (int off = 1; off < PNODES; off <<= 1) {
        int v = 0;
        if (t < PNODES && t >= off) v = lofs[t - off];
        __syncthreads();
        if (t < PNODES) lofs[t] += v;
        __syncthreads();
    }
    if (t < PNODES) {
        int excl = lofs[t] - hist[t];
        cur[t] = excl;
        int node = (b << PSHIFT) + t;
        if (node < n) {
            offsets[node] = base + excl;
            norm[node] = 1.0f / ((float)hist[t] + 1.0f);
        }
    }
    __syncthreads();
    for (int e = t; e < cnt; e += 256) {
        unsigned v = bd[e];
        int local = v >> 17;
        int s = (int)(v & 0x1FFFF);
        int r = atomicAdd(&cur[local], 1);
        cols[base + r] = s;
    }
}

// ---------------- fp32 -> fp16 conversion (row-major bulk) ----------------

__global__ __launch_bounds__(256) void k_cvt(const float* __restrict__ x,
                                             _Float16* __restrict__ y, int total8) {
    int i = blockIdx.x * 256 + threadIdx.x;
    if (i >= total8) return;
    float4 a = ((const float4*)x)[i * 2];
    float4 b = ((const float4*)x)[i * 2 + 1];
    half8 o;
    o[0] = (_Float16)a.x; o[1] = (_Float16)a.y; o[2] = (_Float16)a.z; o[3] = (_Float16)a.w;
    o[4] = (_Float16)b.x; o[5] = (_Float16)b.y; o[6] = (_Float16)b.z; o[7] = (_Float16)b.w;
    ((half8*)y)[i] = o;
}

// ---------------- aggregation (fp16 gather, fp32 accumulate) ----------------
// 128-wide rows (256 B fp16): 16 lanes/node x 8 halves; 16 nodes per 256-thread block.

__global__ __launch_bounds__(256) void k_agg128_f16(const _Float16* __restrict__ h,
                                                    const int* __restrict__ offs,
                                                    const int* __restrict__ cols,
                                                    const float* __restrict__ norm,
                                                    float* __restrict__ t, int n) {
    int node = blockIdx.x * 16 + (threadIdx.x >> 4);
    if (node >= n) return;
    int lane = threadIdx.x & 15;

    half8 sv = ((const half8*)(h + (size_t)node * 128))[lane];
    float acc[8];
#pragma unroll
    for (int j = 0; j < 8; j++) acc[j] = (float)sv[j];

    int p = offs[node], e = offs[node + 1];
    for (; p + 2 <= e; p += 2) {
        int c0 = cols[p], c1 = cols[p + 1];
        half8 a = ((const half8*)(h + (size_t)c0 * 128))[lane];
        half8 b = ((const half8*)(h + (size_t)c1 * 128))[lane];
#pragma unroll
        for (int j = 0; j < 8; j++) acc[j] += (float)a[j] + (float)b[j];
    }
    if (p < e) {
        half8 a = ((const half8*)(h + (size_t)cols[p] * 128))[lane];
#pragma unroll
        for (int j = 0; j < 8; j++) acc[j] += (float)a[j];
    }
    float nm = norm[node];
    float* tp = t + (size_t)node * 128 + lane * 8;
    float4 o0 = make_float4(acc[0] * nm, acc[1] * nm, acc[2] * nm, acc[3] * nm);
    float4 o1 = make_float4(acc[4] * nm, acc[5] * nm, acc[6] * nm, acc[7] * nm);
    *(float4*)tp = o0;
    *(float4*)(tp + 4) = o1;
}

// 64-wide fp16 rows + bias (layer-3 transform-first): 8 lanes/node; 32 nodes/block.
__global__ __launch_bounds__(256) void k_agg64_f16(const _Float16* __restrict__ g,
                                                   const int* __restrict__ offs,
                                                   const int* __restrict__ cols,
                                                   const float* __restrict__ norm,
                                                   const float* __restrict__ bias,
                                                   float* __restrict__ out, int n) {
    int node = blockIdx.x * 32 + (threadIdx.x >> 3);
    if (node >= n) return;
    int lane = threadIdx.x & 7;

    half8 sv = ((const half8*)(g + (size_t)node * 64))[lane];
    float acc[8];
#pragma unroll
    for (int j = 0; j < 8; j++) acc[j] = (float)sv[j];

    int p = offs[node], e = offs[node + 1];
    for (; p + 2 <= e; p += 2) {
        int c0 = cols[p], c1 = cols[p + 1];
        half8 a = ((const half8*)(g + (size_t)c0 * 64))[lane];
        half8 b = ((const half8*)(g + (size_t)c1 * 64))[lane];
#pragma unroll
        for (int j = 0; j < 8; j++) acc[j] += (float)a[j] + (float)b[j];
    }
    if (p < e) {
        half8 a = ((const half8*)(g + (size_t)cols[p] * 64))[lane];
#pragma unroll
        for (int j = 0; j < 8; j++) acc[j] += (float)a[j];
    }
    float nm = norm[node];
    float4 bb0 = ((const float4*)bias)[lane * 2];
    float4 bb1 = ((const float4*)bias)[lane * 2 + 1];
    float* op = out + (size_t)node * 64 + lane * 8;
    *(float4*)op = make_float4(acc[0] * nm + bb0.x, acc[1] * nm + bb0.y,
                               acc[2] * nm + bb0.z, acc[3] * nm + bb0.w);
    *(float4*)(op + 4) = make_float4(acc[4] * nm + bb1.x, acc[5] * nm + bb1.y,
                                     acc[6] * nm + bb1.z, acc[7] * nm + bb1.w);
}

// ---------------- GEMM: out[m][j] = act(dot(A[m][:128], W[j][:128]) [+ b[j]]) ----------------

template <int KOUT, bool RELU, bool BIAS, bool OUT_HALF>
__global__ __launch_bounds__(256) void k_gemm(const float* __restrict__ A,
                                              const float* __restrict__ W,
                                              const float* __restrict__ bias,
                                              void* __restrict__ outv, int n) {
    constexpr int TN = (KOUT == 128) ? 8 : 4;
    __shared__ __align__(16) float tA[32][128];
    __shared__ __align__(16) float WT[32][KOUT];

    int tid  = threadIdx.x;
    int trow = tid >> 4;
    int tcol = tid & 15;
    int m0   = blockIdx.x * 128;
    int mt   = trow * 8;
    int j0   = tcol * TN;
    int sw   = ((j0 >> 5) & 3) << 2;

    float acc[8][TN];
#pragma unroll
    for (int i = 0; i < 8; i++)
#pragma unroll
        for (int j = 0; j < TN; j++) acc[i][j] = 0.f;

    for (int k0 = 0; k0 < 128; k0 += 32) {
        __syncthreads();
#pragma unroll
        for (int j = 0; j < 4; j++) {
            int idx = tid * 4 + j;
            int q = idx & 7, m = idx >> 3;
            int gm = m0 + m;
            float4 v = make_float4(0.f, 0.f, 0.f, 0.f);
            if (gm < n) v = *(const float4*)(A + (size_t)gm * 128 + k0 + q * 4);
            tA[q * 4 + 0][m] = v.x;
            tA[q * 4 + 1][m] = v.y;
            tA[q * 4 + 2][m] = v.z;
            tA[q * 4 + 3][m] = v.w;
        }
#pragma unroll
        for (int j = 0; j < KOUT / 32; j++) {
            int idx = tid * (KOUT / 32) + j;
            int q = idx & 7, jj = idx >> 3;
            float4 v = *(const float4*)(W + (size_t)jj * 128 + k0 + q * 4);
            int js = jj ^ (((jj >> 5) & 3) << 2);
            WT[q * 4 + 0][js] = v.x;
            WT[q * 4 + 1][js] = v.y;
            WT[q * 4 + 2][js] = v.z;
            WT[q * 4 + 3][js] = v.w;
        }
        __syncthreads();

#pragma unroll
        for (int k = 0; k < 32; k++) {
            float a[8], b[TN];
            *(float4*)&a[0] = *(const float4*)&tA[k][mt];
            *(float4*)&a[4] = *(const float4*)&tA[k][mt + 4];
            *(float4*)&b[0] = *(const float4*)&WT[k][j0 ^ sw];
            if constexpr (TN == 8)
                *(float4*)&b[4] = *(const float4*)&WT[k][(j0 + 4) ^ sw];
#pragma unroll
            for (int i = 0; i < 8; i++)
#pragma unroll
                for (int j = 0; j < TN; j++) acc[i][j] = fmaf(a[i], b[j], acc[i][j]);
        }
    }

    float bj[TN];
#pragma unroll
    for (int j = 0; j < TN; j++) bj[j] = BIAS ? bias[j0 + j] : 0.f;

#pragma unroll
    for (int i = 0; i < 8; i++) {
        int gm = m0 + mt + i;
        if (gm < n) {
            float o[TN];
#pragma unroll
            for (int j = 0; j < TN; j++) {
                float v = acc[i][j] + bj[j];
                if (RELU) v = fmaxf(v, 0.f);
                o[j] = v;
            }
            if constexpr (OUT_HALF) {
                _Float16* op = (_Float16*)outv + (size_t)gm * KOUT + j0;
                if constexpr (TN == 8) {
                    half8 o8;
#pragma unroll
                    for (int j = 0; j < 8; j++) o8[j] = (_Float16)o[j];
                    *(half8*)op = o8;
                } else {
                    half4 o4;
#pragma unroll
                    for (int j = 0; j < 4; j++) o4[j] = (_Float16)o[j];
                    *(half4*)op = o4;
                }
            } else {
                float* op = (float*)outv + (size_t)gm * KOUT + j0;
                *(float4*)&op[0] = *(const float4*)&o[0];
                if constexpr (TN == 8) *(float4*)&op[4] = *(const float4*)&o[4];
            }
        }
    }
}

// ---------------- launch ----------------

extern "C" void kernel_launch(void* const* d_in, const int* in_sizes, int n_in,
                              void* d_out, int out_size, void* d_ws, size_t ws_size,
                              hipStream_t stream) {
    const float* x  = (const float*)d_in[0];
    const int*  src = (const int*)d_in[1];
    const int*  dst = (const int*)d_in[2];
    const float* W1 = (const float*)d_in[3];
    const float* b1 = (const float*)d_in[4];
    const float* W2 = (const float*)d_in[5];
    const float* b2 = (const float*)d_in[6];
    const float* W3 = (const float*)d_in[7];
    const float* b3 = (const float*)d_in[8];
    float* out = (float*)d_out;

    int n = in_sizes[0] / 128;
    int E = in_sizes[1];
    int B = (n + PNODES - 1) >> PSHIFT;
    int total = B * NBLK;
    int chunk = (E + NBLK - 1) / NBLK;
    int G1 = (total + 1023) / 1024;  // 98 for n=100k (must be <= 128)

    char* ws = (char*)d_ws;
    size_t off = 0;
    auto alloc = [&](size_t bytes) -> char* {
        char* p = ws + off;
        off += (bytes + 255) & ~(size_t)255;
        return p;
    };
    int*   bbase   = (int*)alloc(((size_t)B + 1) * 4);
    int*   offsets = (int*)alloc(((size_t)n + 1) * 4);
    float* norm    = (float*)alloc((size_t)n * 4);
    int*   psum    = (int*)alloc(256 * 4);
    int*   pbase   = (int*)alloc(256 * 4);
    int*   cols    = (int*)alloc((size_t)E * 4);
    float* tbuf    = (float*)alloc((size_t)n * 128 * 4);
    float* hbuf    = (float*)alloc((size_t)n * 128 * 4);

    // aliases (all uses strictly sequenced; see dataflow):
    unsigned int* ebuf  = (unsigned int*)tbuf;                     // CSR entries, 6.4 MB
    int*          histT = (int*)(tbuf + (size_t)2 * 1024 * 1024);  // +8 MB, 400 KB
    _Float16*     x16   = (_Float16*)hbuf;  // fp16(x); dead after L1 aggregate
    _Float16*     h16   = (_Float16*)hbuf;  // fp16 h1 (gemm1 out); dead after L2 aggregate
    _Float16*     g16   = (_Float16*)tbuf;  // fp16 g (gemm3 out); tbuf free by then

    // CSR build
    k_hist <<<NBLK, 512, 0, stream>>>(dst, E, chunk, B, histT);
    k_scanA<<<G1, 256, 0, stream>>>(histT, total, psum);
    k_scanB<<<1, 128, 0, stream>>>(psum, G1, pbase, bbase, B, offsets, n, E);
    k_scanC<<<G1, 256, 0, stream>>>(histT, total, pbase, bbase);
    k_place<<<NBLK, 512, 0, stream>>>(src, dst, histT, E, chunk, B, ebuf);
    k_binB <<<B, 256, 0, stream>>>(ebuf, bbase, offsets, norm, cols, n);

    // x -> fp16
    int total8 = n * 16;  // n*128/8
    k_cvt<<<(total8 + 255) / 256, 256, 0, stream>>>(x, x16, total8);

    int nblkA  = (n + 15) / 16;
    int nblkA6 = (n + 31) / 32;
    int nblkG  = (n + 127) / 128;

    // layer 1: agg(x16) -> t1 ; gemm -> h1 (fp16)
    k_agg128_f16<<<nblkA, 256, 0, stream>>>(x16, offsets, cols, norm, tbuf, n);
    k_gemm<128, true, true, true><<<nblkG, 256, 0, stream>>>(tbuf, W1, b1, h16, n);
    // layer 2: agg(h16) -> t2 ; gemm -> h2 (fp32, hbuf)
    k_agg128_f16<<<nblkA, 256, 0, stream>>>(h16, offsets, cols, norm, tbuf, n);
    k_gemm<128, true, true, false><<<nblkG, 256, 0, stream>>>(tbuf, W2, b2, hbuf, n);
    // layer 3 (transform-first): g16 = h2 @ W3^T ; out = (g+sum g)*norm + b3
    k_gemm<64, false, false, true><<<nblkG, 256, 0, stream>>>(hbuf, W3, b3, g16, n);
    k_agg64_f16<<<nblkA6, 256, 0, stream>>>(g16, offsets, cols, norm, b3, out, n);
}

// Round 5
// 283.021 us; speedup vs baseline: 2.4521x; 1.3228x over previous
//
#include <hip/hip_runtime.h>
#include <hip/hip_fp16.h>

typedef _Float16 f16x8 __attribute__((ext_vector_type(8)));
typedef _Float16 f16x4 __attribute__((ext_vector_type(4)));
typedef float    f32x4 __attribute__((ext_vector_type(4)));

// ---------------- CSR build: block-private two-pass counting sort ----------------
// Coarse buckets of 64 dst nodes; packed entry (local_dst<<17)|src (needs n <= 131072).

#define PSHIFT 6
#define PNODES 64
#define BMAX   2048
#define NBLK   64

__global__ __launch_bounds__(512) void k_hist(const int* __restrict__ dst, int E, int chunk,
                                              int B, int* __restrict__ histT) {
    __shared__ int hist[BMAX];
    int blk = blockIdx.x, t = threadIdx.x;
    for (int k = t; k < B; k += 512) hist[k] = 0;
    __syncthreads();
    int lo = blk * chunk, hi = min(lo + chunk, E);
    for (int i = lo + t; i < hi; i += 512) atomicAdd(&hist[dst[i] >> PSHIFT], 1);
    __syncthreads();
    for (int k = t; k < B; k += 512) histT[k * NBLK + blk] = hist[k];
}

__global__ __launch_bounds__(256) void k_scanA(const int* __restrict__ histT, int total,
                                               int* __restrict__ psum) {
    __shared__ int sd[256];
    int t = threadIdx.x;
    int base = blockIdx.x * 1024 + t * 4;
    int s = 0;
    if (base + 3 < total) {
        int4 v = *(const int4*)(histT + base);
        s = v.x + v.y + v.z + v.w;
    } else {
        for (int j = 0; j < 4; j++) if (base + j < total) s += histT[base + j];
    }
    sd[t] = s;
    __syncthreads();
    for (int off = 128; off > 0; off >>= 1) {
        if (t < off) sd[t] += sd[t + off];
        __syncthreads();
    }
    if (t == 0) psum[blockIdx.x] = sd[0];
}

__global__ __launch_bounds__(128) void k_scanB(const int* __restrict__ psum, int G,
                                               int* __restrict__ pbase,
                                               int* __restrict__ bbase, int B,
                                               int* __restrict__ offsets, int n, int E) {
    __shared__ int sd[128];
    int t = threadIdx.x;
    int v = (t < G) ? psum[t] : 0;
    sd[t] = v;
    __syncthreads();
    int acc = v;
    for (int off = 1; off < 128; off <<= 1) {
        int u = (t >= off) ? sd[t - off] : 0;
        __syncthreads();
        acc += u;
        sd[t] = acc;
        __syncthreads();
    }
    if (t < G) pbase[t] = acc - v;
    if (t == 0) { bbase[B] = E; offsets[n] = E; }
}

__global__ __launch_bounds__(256) void k_scanC(int* __restrict__ histT, int total,
                                               const int* __restrict__ pbase,
                                               int* __restrict__ bbase) {
    __shared__ int sd[256];
    int t = threadIdx.x;
    int base = blockIdx.x * 1024 + t * 4;
    int v[4];
    int s = 0;
    bool full = (base + 3 < total);
    if (full) {
        int4 q = *(const int4*)(histT + base);
        v[0] = q.x; v[1] = q.y; v[2] = q.z; v[3] = q.w;
        s = q.x + q.y + q.z + q.w;
    } else {
#pragma unroll
        for (int j = 0; j < 4; j++) { v[j] = (base + j < total) ? histT[base + j] : 0; s += v[j]; }
    }
    sd[t] = s;
    __syncthreads();
    int acc = s;
    for (int off = 1; off < 256; off <<= 1) {
        int u = (t >= off) ? sd[t - off] : 0;
        __syncthreads();
        acc += u;
        sd[t] = acc;
        __syncthreads();
    }
    int run = pbase[blockIdx.x] + (acc - s);
    int o[4];
#pragma unroll
    for (int j = 0; j < 4; j++) { o[j] = run; run += v[j]; }
    if (full) *(int4*)(histT + base) = make_int4(o[0], o[1], o[2], o[3]);
    else { for (int j = 0; j < 4; j++) if (base + j < total) histT[base + j] = o[j]; }
    if ((base & 63) == 0 && base < total) bbase[base >> 6] = o[0];
}

__global__ __launch_bounds__(512) void k_place(const int* __restrict__ src,
                                               const int* __restrict__ dst,
                                               const int* __restrict__ histT,
                                               int E, int chunk, int B,
                                               unsigned int* __restrict__ ebuf) {
    __shared__ int cur[BMAX];
    int blk = blockIdx.x, t = threadIdx.x;
    for (int k = t; k < B; k += 512) cur[k] = histT[k * NBLK + blk];
    __syncthreads();
    int lo = blk * chunk, hi = min(lo + chunk, E);
    for (int i = lo + t; i < hi; i += 512) {
        int d = dst[i], s = src[i];
        int k = d >> PSHIFT;
        int pos = atomicAdd(&cur[k], 1);
        ebuf[pos] = ((unsigned)(d & (PNODES - 1)) << 17) | (unsigned)s;
    }
}

__global__ __launch_bounds__(256) void k_binB(const unsigned int* __restrict__ ebuf,
                                              const int* __restrict__ bbase,
                                              int* __restrict__ offsets,
                                              float* __restrict__ norm,
                                              int* __restrict__ cols, int n) {
    __shared__ int hist[PNODES];
    __shared__ int lofs[PNODES];
    __shared__ int cur[PNODES];
    int b = blockIdx.x;
    int t = threadIdx.x;
    int base = bbase[b];
    int cnt = bbase[b + 1] - base;
    const unsigned int* bd = ebuf + base;

    if (t < PNODES) hist[t] = 0;
    __syncthreads();
    for (int e = t; e < cnt; e += 256) atomicAdd(&hist[bd[e] >> 17], 1);
    __syncthreads();
    if (t < PNODES) lofs[t] = hist[t];
    __syncthreads();
    for (int off = 1; off < PNODES; off <<= 1) {
        int v = 0;
        if (t < PNODES && t >= off) v = lofs[t - off];
        __syncthreads();
        if (t < PNODES) lofs[t] += v;
        __syncthreads();
    }
    if (t < PNODES) {
        int excl = lofs[t] - hist[t];
        cur[t] = excl;
        int node = (b << PSHIFT) + t;
        if (node < n) {
            offsets[node] = base + excl;
            norm[node] = 1.0f / ((float)hist[t] + 1.0f);
        }
    }
    __syncthreads();
    for (int e = t; e < cnt; e += 256) {
        unsigned v = bd[e];
        int local = v >> 17;
        int s = (int)(v & 0x1FFFF);
        int r = atomicAdd(&cur[local], 1);
        cols[base + r] = s;
    }
}

// ---------------- fp32 -> fp16 bulk convert (for weights) ----------------

__global__ __launch_bounds__(256) void k_cvt(const float* __restrict__ x,
                                             _Float16* __restrict__ y, int total8) {
    int i = blockIdx.x * 256 + threadIdx.x;
    if (i >= total8) return;
    float4 a = ((const float4*)x)[i * 2];
    float4 b = ((const float4*)x)[i * 2 + 1];
    f16x8 o;
    o[0] = (_Float16)a.x; o[1] = (_Float16)a.y; o[2] = (_Float16)a.z; o[3] = (_Float16)a.w;
    o[4] = (_Float16)b.x; o[5] = (_Float16)b.y; o[6] = (_Float16)b.z; o[7] = (_Float16)b.w;
    ((f16x8*)y)[i] = o;
}

// ---------------- MFMA GEMM: g[m][j] = dot(A[m][:128], W[j][:128]) (no bias/act) ----------------
// Block: 256 threads (4 waves), tile 128 rows x KOUT cols. fp16 operands, fp32 accum.
// v_mfma_f32_16x16x16_f16: A/B lane l holds [l&15][(l>>4)*4+j]; D row=(l>>4)*4+reg, col=l&15.

template <int KOUT, bool IN_F32>
__global__ __launch_bounds__(256) void k_gemm_mfma(const void* __restrict__ Ain,
                                                   const _Float16* __restrict__ Wh,
                                                   _Float16* __restrict__ outh, int n) {
    constexpr int NT = KOUT / 16;
    __shared__ _Float16 A_lds[128 * 136];   // row stride 136 halves (272 B): <=2-way banks
    __shared__ _Float16 W_lds[KOUT * 136];

    int tid  = threadIdx.x;
    int lane = tid & 63;
    int wave = tid >> 6;
    int m0   = blockIdx.x * 128;

    // stage W [KOUT][128]
    for (int i = tid; i < KOUT * 16; i += 256) {
        int r = i >> 4, c = i & 15;
        *(f16x8*)&W_lds[r * 136 + c * 8] = ((const f16x8*)(Wh + r * 128))[c];
    }
    // stage A tile [128][128]
    if constexpr (IN_F32) {
        const float* A = (const float*)Ain;
        for (int i = tid; i < 2048; i += 256) {
            int r = i >> 4, c = i & 15;
            int gm = m0 + r;
            f16x8 v = {};
            if (gm < n) {
                float4 u0 = *(const float4*)(A + (size_t)gm * 128 + c * 8);
                float4 u1 = *(const float4*)(A + (size_t)gm * 128 + c * 8 + 4);
                v[0] = (_Float16)u0.x; v[1] = (_Float16)u0.y;
                v[2] = (_Float16)u0.z; v[3] = (_Float16)u0.w;
                v[4] = (_Float16)u1.x; v[5] = (_Float16)u1.y;
                v[6] = (_Float16)u1.z; v[7] = (_Float16)u1.w;
            }
            *(f16x8*)&A_lds[r * 136 + c * 8] = v;
        }
    } else {
        const _Float16* A = (const _Float16*)Ain;
        for (int i = tid; i < 2048; i += 256) {
            int r = i >> 4, c = i & 15;
            int gm = m0 + r;
            f16x8 v = {};
            if (gm < n) v = ((const f16x8*)(A + (size_t)gm * 128))[c];
            *(f16x8*)&A_lds[r * 136 + c * 8] = v;
        }
    }
    __syncthreads();

    int m0w = wave * 32;
    int lr  = lane & 15;
    int lk  = (lane >> 4) * 4;

    f32x4 acc[2][NT];
#pragma unroll
    for (int mi = 0; mi < 2; mi++)
#pragma unroll
        for (int ni = 0; ni < NT; ni++) acc[mi][ni] = (f32x4){0.f, 0.f, 0.f, 0.f};

#pragma unroll
    for (int kk = 0; kk < 8; kk++) {
        int k0 = kk * 16;
        f16x4 a0 = *(const f16x4*)&A_lds[(m0w + lr) * 136 + k0 + lk];
        f16x4 a1 = *(const f16x4*)&A_lds[(m0w + 16 + lr) * 136 + k0 + lk];
#pragma unroll
        for (int ni = 0; ni < NT; ni++) {
            f16x4 b = *(const f16x4*)&W_lds[(ni * 16 + lr) * 136 + k0 + lk];
            acc[0][ni] = __builtin_amdgcn_mfma_f32_16x16x16f16(a0, b, acc[0][ni], 0, 0, 0);
            acc[1][ni] = __builtin_amdgcn_mfma_f32_16x16x16f16(a1, b, acc[1][ni], 0, 0, 0);
        }
    }

    int orow = (lane >> 4) * 4;
#pragma unroll
    for (int mi = 0; mi < 2; mi++) {
#pragma unroll
        for (int r = 0; r < 4; r++) {
            int gm = m0 + m0w + mi * 16 + orow + r;
            if (gm < n) {
                _Float16* op = outh + (size_t)gm * KOUT + lr;
#pragma unroll
                for (int ni = 0; ni < NT; ni++)
                    op[ni * 16] = (_Float16)acc[mi][ni][r];
            }
        }
    }
}

// ---------------- aggregation on g: h = act((g[v] + sum_in g[c])*norm + bias) ----------------
// 128-wide fp16 rows: 16 lanes/node, 16 nodes per 256-thread block. Unroll 4.

__global__ __launch_bounds__(256) void k_agg128_br(const _Float16* __restrict__ g,
                                                   const int* __restrict__ offs,
                                                   const int* __restrict__ cols,
                                                   const float* __restrict__ norm,
                                                   const float* __restrict__ bias,
                                                   _Float16* __restrict__ hout, int n) {
    int node = blockIdx.x * 16 + (threadIdx.x >> 4);
    if (node >= n) return;
    int lane = threadIdx.x & 15;

    f16x8 sv = ((const f16x8*)(g + (size_t)node * 128))[lane];
    float acc[8];
#pragma unroll
    for (int j = 0; j < 8; j++) acc[j] = (float)sv[j];

    int p = offs[node], e = offs[node + 1];
    for (; p + 4 <= e; p += 4) {
        int c0 = cols[p], c1 = cols[p + 1], c2 = cols[p + 2], c3 = cols[p + 3];
        f16x8 a0 = ((const f16x8*)(g + (size_t)c0 * 128))[lane];
        f16x8 a1 = ((const f16x8*)(g + (size_t)c1 * 128))[lane];
        f16x8 a2 = ((const f16x8*)(g + (size_t)c2 * 128))[lane];
        f16x8 a3 = ((const f16x8*)(g + (size_t)c3 * 128))[lane];
#pragma unroll
        for (int j = 0; j < 8; j++)
            acc[j] += ((float)a0[j] + (float)a1[j]) + ((float)a2[j] + (float)a3[j]);
    }
    for (; p < e; p++) {
        f16x8 a = ((const f16x8*)(g + (size_t)cols[p] * 128))[lane];
#pragma unroll
        for (int j = 0; j < 8; j++) acc[j] += (float)a[j];
    }
    float nm = norm[node];
    float4 bb0 = ((const float4*)bias)[lane * 2];
    float4 bb1 = ((const float4*)bias)[lane * 2 + 1];
    float o[8];
    o[0] = acc[0] * nm + bb0.x; o[1] = acc[1] * nm + bb0.y;
    o[2] = acc[2] * nm + bb0.z; o[3] = acc[3] * nm + bb0.w;
    o[4] = acc[4] * nm + bb1.x; o[5] = acc[5] * nm + bb1.y;
    o[6] = acc[6] * nm + bb1.z; o[7] = acc[7] * nm + bb1.w;
    f16x8 ov;
#pragma unroll
    for (int j = 0; j < 8; j++) ov[j] = (_Float16)fmaxf(o[j], 0.f);
    ((f16x8*)(hout + (size_t)node * 128))[lane] = ov;
}

// 64-wide final: out = (g[v] + sum_in g[c])*norm + bias (fp32 out, no relu)
__global__ __launch_bounds__(256) void k_agg64_b(const _Float16* __restrict__ g,
                                                 const int* __restrict__ offs,
                                                 const int* __restrict__ cols,
                                                 const float* __restrict__ norm,
                                                 const float* __restrict__ bias,
                                                 float* __restrict__ out, int n) {
    int node = blockIdx.x * 32 + (threadIdx.x >> 3);
    if (node >= n) return;
    int lane = threadIdx.x & 7;

    f16x8 sv = ((const f16x8*)(g + (size_t)node * 64))[lane];
    float acc[8];
#pragma unroll
    for (int j = 0; j < 8; j++) acc[j] = (float)sv[j];

    int p = offs[node], e = offs[node + 1];
    for (; p + 4 <= e; p += 4) {
        int c0 = cols[p], c1 = cols[p + 1], c2 = cols[p + 2], c3 = cols[p + 3];
        f16x8 a0 = ((const f16x8*)(g + (size_t)c0 * 64))[lane];
        f16x8 a1 = ((const f16x8*)(g + (size_t)c1 * 64))[lane];
        f16x8 a2 = ((const f16x8*)(g + (size_t)c2 * 64))[lane];
        f16x8 a3 = ((const f16x8*)(g + (size_t)c3 * 64))[lane];
#pragma unroll
        for (int j = 0; j < 8; j++)
            acc[j] += ((float)a0[j] + (float)a1[j]) + ((float)a2[j] + (float)a3[j]);
    }
    for (; p < e; p++) {
        f16x8 a = ((const f16x8*)(g + (size_t)cols[p] * 64))[lane];
#pragma unroll
        for (int j = 0; j < 8; j++) acc[j] += (float)a[j];
    }
    float nm = norm[node];
    float4 bb0 = ((const float4*)bias)[lane * 2];
    float4 bb1 = ((const float4*)bias)[lane * 2 + 1];
    float* op = out + (size_t)node * 64 + lane * 8;
    *(float4*)op = make_float4(acc[0] * nm + bb0.x, acc[1] * nm + bb0.y,
                               acc[2] * nm + bb0.z, acc[3] * nm + bb0.w);
    *(float4*)(op + 4) = make_float4(acc[4] * nm + bb1.x, acc[5] * nm + bb1.y,
                                     acc[6] * nm + bb1.z, acc[7] * nm + bb1.w);
}

// ---------------- launch ----------------

extern "C" void kernel_launch(void* const* d_in, const int* in_sizes, int n_in,
                              void* d_out, int out_size, void* d_ws, size_t ws_size,
                              hipStream_t stream) {
    const float* x  = (const float*)d_in[0];
    const int*  src = (const int*)d_in[1];
    const int*  dst = (const int*)d_in[2];
    const float* W1 = (const float*)d_in[3];
    const float* b1 = (const float*)d_in[4];
    const float* W2 = (const float*)d_in[5];
    const float* b2 = (const float*)d_in[6];
    const float* W3 = (const float*)d_in[7];
    const float* b3 = (const float*)d_in[8];
    float* out = (float*)d_out;

    int n = in_sizes[0] / 128;
    int E = in_sizes[1];
    int B = (n + PNODES - 1) >> PSHIFT;
    int total = B * NBLK;
    int chunk = (E + NBLK - 1) / NBLK;
    int G1 = (total + 1023) / 1024;

    char* ws = (char*)d_ws;
    size_t off = 0;
    auto alloc = [&](size_t bytes) -> char* {
        char* p = ws + off;
        off += (bytes + 255) & ~(size_t)255;
        return p;
    };
    int*      bbase   = (int*)alloc(((size_t)B + 1) * 4);
    int*      offsets = (int*)alloc(((size_t)n + 1) * 4);
    float*    norm    = (float*)alloc((size_t)n * 4);
    int*      psum    = (int*)alloc(256 * 4);
    int*      pbase   = (int*)alloc(256 * 4);
    int*      cols    = (int*)alloc((size_t)E * 4);
    _Float16* w1h     = (_Float16*)alloc(128 * 128 * 2);
    _Float16* w2h     = (_Float16*)alloc(128 * 128 * 2);
    _Float16* w3h     = (_Float16*)alloc(64 * 128 * 2);
    _Float16* bufA    = (_Float16*)alloc((size_t)n * 128 * 2);
    _Float16* bufB    = (_Float16*)alloc((size_t)n * 128 * 2);

    // CSR scratch aliases bufA (dead until gemm1 output):
    unsigned int* ebuf  = (unsigned int*)bufA;                          // 6.4 MB
    int*          histT = (int*)((char*)bufA + (size_t)8 * 1024 * 1024); // 400 KB

    // weights -> fp16 (independent of CSR build)
    k_cvt<<<8, 256, 0, stream>>>(W1, w1h, 2048);
    k_cvt<<<8, 256, 0, stream>>>(W2, w2h, 2048);
    k_cvt<<<4, 256, 0, stream>>>(W3, w3h, 1024);

    // CSR build
    k_hist <<<NBLK, 512, 0, stream>>>(dst, E, chunk, B, histT);
    k_scanA<<<G1, 256, 0, stream>>>(histT, total, psum);
    k_scanB<<<1, 128, 0, stream>>>(psum, G1, pbase, bbase, B, offsets, n, E);
    k_scanC<<<G1, 256, 0, stream>>>(histT, total, pbase, bbase);
    k_place<<<NBLK, 512, 0, stream>>>(src, dst, histT, E, chunk, B, ebuf);
    k_binB <<<B, 256, 0, stream>>>(ebuf, bbase, offsets, norm, cols, n);

    int nblkG  = (n + 127) / 128;
    int nblkA  = (n + 15) / 16;
    int nblkA6 = (n + 31) / 32;

    // layer 1 (transform-first): g1 = x @ W1^T ; h1 = relu(agg(g1)*norm + b1)
    k_gemm_mfma<128, true><<<nblkG, 256, 0, stream>>>(x, w1h, bufA, n);
    k_agg128_br<<<nblkA, 256, 0, stream>>>(bufA, offsets, cols, norm, b1, bufB, n);
    // layer 2: g2 = h1 @ W2^T ; h2 = relu(agg(g2)*norm + b2)
    k_gemm_mfma<128, false><<<nblkG, 256, 0, stream>>>(bufB, w2h, bufA, n);
    k_agg128_br<<<nblkA, 256, 0, stream>>>(bufA, offsets, cols, norm, b2, bufB, n);
    // layer 3: g3 = h2 @ W3^T ; out = agg64(g3)*norm + b3
    k_gemm_mfma<64, false><<<nblkG, 256, 0, stream>>>(bufB, w3h, bufA, n);
    k_agg64_b<<<nblkA6, 256, 0, stream>>>(bufA, offsets, cols, norm, b3, out, n);
}

// Round 6
// 280.282 us; speedup vs baseline: 2.4761x; 1.0098x over previous
//
#include <hip/hip_runtime.h>
#include <hip/hip_fp16.h>

typedef _Float16 f16x8 __attribute__((ext_vector_type(8)));
typedef _Float16 f16x4 __attribute__((ext_vector_type(4)));
typedef float    f32x4 __attribute__((ext_vector_type(4)));

// ---------------- CSR build: block-private two-pass counting sort ----------------
// Coarse buckets of 64 dst nodes; packed entry (local_dst<<17)|src (needs n <= 131072).

#define PSHIFT 6
#define PNODES 64
#define BMAX   2048
#define NBLK   64

__global__ __launch_bounds__(512) void k_hist(const int* __restrict__ dst, int E, int chunk,
                                              int B, int* __restrict__ histT) {
    __shared__ int hist[BMAX];
    int blk = blockIdx.x, t = threadIdx.x;
    for (int k = t; k < B; k += 512) hist[k] = 0;
    __syncthreads();
    int lo = blk * chunk, hi = min(lo + chunk, E);
    for (int i = lo + t; i < hi; i += 512) atomicAdd(&hist[dst[i] >> PSHIFT], 1);
    __syncthreads();
    for (int k = t; k < B; k += 512) histT[k * NBLK + blk] = hist[k];
}

__global__ __launch_bounds__(256) void k_scanA(const int* __restrict__ histT, int total,
                                               int* __restrict__ psum) {
    __shared__ int sd[256];
    int t = threadIdx.x;
    int base = blockIdx.x * 1024 + t * 4;
    int s = 0;
    if (base + 3 < total) {
        int4 v = *(const int4*)(histT + base);
        s = v.x + v.y + v.z + v.w;
    } else {
        for (int j = 0; j < 4; j++) if (base + j < total) s += histT[base + j];
    }
    sd[t] = s;
    __syncthreads();
    for (int off = 128; off > 0; off >>= 1) {
        if (t < off) sd[t] += sd[t + off];
        __syncthreads();
    }
    if (t == 0) psum[blockIdx.x] = sd[0];
}

__global__ __launch_bounds__(128) void k_scanB(const int* __restrict__ psum, int G,
                                               int* __restrict__ pbase,
                                               int* __restrict__ bbase, int B,
                                               int* __restrict__ offsets, int n, int E) {
    __shared__ int sd[128];
    int t = threadIdx.x;
    int v = (t < G) ? psum[t] : 0;
    sd[t] = v;
    __syncthreads();
    int acc = v;
    for (int off = 1; off < 128; off <<= 1) {
        int u = (t >= off) ? sd[t - off] : 0;
        __syncthreads();
        acc += u;
        sd[t] = acc;
        __syncthreads();
    }
    if (t < G) pbase[t] = acc - v;
    if (t == 0) { bbase[B] = E; offsets[n] = E; }
}

__global__ __launch_bounds__(256) void k_scanC(int* __restrict__ histT, int total,
                                               const int* __restrict__ pbase,
                                               int* __restrict__ bbase) {
    __shared__ int sd[256];
    int t = threadIdx.x;
    int base = blockIdx.x * 1024 + t * 4;
    int v[4];
    int s = 0;
    bool full = (base + 3 < total);
    if (full) {
        int4 q = *(const int4*)(histT + base);
        v[0] = q.x; v[1] = q.y; v[2] = q.z; v[3] = q.w;
        s = q.x + q.y + q.z + q.w;
    } else {
#pragma unroll
        for (int j = 0; j < 4; j++) { v[j] = (base + j < total) ? histT[base + j] : 0; s += v[j]; }
    }
    sd[t] = s;
    __syncthreads();
    int acc = s;
    for (int off = 1; off < 256; off <<= 1) {
        int u = (t >= off) ? sd[t - off] : 0;
        __syncthreads();
        acc += u;
        sd[t] = acc;
        __syncthreads();
    }
    int run = pbase[blockIdx.x] + (acc - s);
    int o[4];
#pragma unroll
    for (int j = 0; j < 4; j++) { o[j] = run; run += v[j]; }
    if (full) *(int4*)(histT + base) = make_int4(o[0], o[1], o[2], o[3]);
    else { for (int j = 0; j < 4; j++) if (base + j < total) histT[base + j] = o[j]; }
    if ((base & 63) == 0 && base < total) bbase[base >> 6] = o[0];
}

__global__ __launch_bounds__(512) void k_place(const int* __restrict__ src,
                                               const int* __restrict__ dst,
                                               const int* __restrict__ histT,
                                               int E, int chunk, int B,
                                               unsigned int* __restrict__ ebuf) {
    __shared__ int cur[BMAX];
    int blk = blockIdx.x, t = threadIdx.x;
    for (int k = t; k < B; k += 512) cur[k] = histT[k * NBLK + blk];
    __syncthreads();
    int lo = blk * chunk, hi = min(lo + chunk, E);
    for (int i = lo + t; i < hi; i += 512) {
        int d = dst[i], s = src[i];
        int k = d >> PSHIFT;
        int pos = atomicAdd(&cur[k], 1);
        ebuf[pos] = ((unsigned)(d & (PNODES - 1)) << 17) | (unsigned)s;
    }
}

__global__ __launch_bounds__(256) void k_binB(const unsigned int* __restrict__ ebuf,
                                              const int* __restrict__ bbase,
                                              int* __restrict__ offsets,
                                              float* __restrict__ norm,
                                              int* __restrict__ cols, int n) {
    __shared__ int hist[PNODES];
    __shared__ int lofs[PNODES];
    __shared__ int cur[PNODES];
    int b = blockIdx.x;
    int t = threadIdx.x;
    int base = bbase[b];
    int cnt = bbase[b + 1] - base;
    const unsigned int* bd = ebuf + base;

    if (t < PNODES) hist[t] = 0;
    __syncthreads();
    for (int e = t; e < cnt; e += 256) atomicAdd(&hist[bd[e] >> 17], 1);
    __syncthreads();
    if (t < PNODES) lofs[t] = hist[t];
    __syncthreads();
    for (int off = 1; off < PNODES; off <<= 1) {
        int v = 0;
        if (t < PNODES && t >= off) v = lofs[t - off];
        __syncthreads();
        if (t < PNODES) lofs[t] += v;
        __syncthreads();
    }
    if (t < PNODES) {
        int excl = lofs[t] - hist[t];
        cur[t] = excl;
        int node = (b << PSHIFT) + t;
        if (node < n) {
            offsets[node] = base + excl;
            norm[node] = 1.0f / ((float)hist[t] + 1.0f);
        }
    }
    __syncthreads();
    for (int e = t; e < cnt; e += 256) {
        unsigned v = bd[e];
        int local = v >> 17;
        int s = (int)(v & 0x1FFFF);
        int r = atomicAdd(&cur[local], 1);
        cols[base + r] = s;
    }
}

// ---------------- MFMA GEMM: g[m][j] = dot(A[m][:128], W[j][:128]) (no bias/act) ----------------
// Block: 256 threads (4 waves), tile 128 rows x KOUT cols. fp16 operands, fp32 accum.
// W is fp32 in global; converted to fp16 during LDS staging (W tile is L2-resident).

template <int KOUT, bool IN_F32>
__global__ __launch_bounds__(256) void k_gemm_mfma(const void* __restrict__ Ain,
                                                   const float* __restrict__ W,
                                                   _Float16* __restrict__ outh, int n) {
    constexpr int NT = KOUT / 16;
    __shared__ _Float16 A_lds[128 * 136];   // row stride 136 halves (272 B): <=2-way banks
    __shared__ _Float16 W_lds[KOUT * 136];

    int tid  = threadIdx.x;
    int lane = tid & 63;
    int wave = tid >> 6;
    int m0   = blockIdx.x * 128;

    // stage W [KOUT][128], fp32 -> fp16
    for (int i = tid; i < KOUT * 16; i += 256) {
        int r = i >> 4, c = i & 15;
        float4 u0 = *(const float4*)(W + (size_t)r * 128 + c * 8);
        float4 u1 = *(const float4*)(W + (size_t)r * 128 + c * 8 + 4);
        f16x8 v;
        v[0] = (_Float16)u0.x; v[1] = (_Float16)u0.y;
        v[2] = (_Float16)u0.z; v[3] = (_Float16)u0.w;
        v[4] = (_Float16)u1.x; v[5] = (_Float16)u1.y;
        v[6] = (_Float16)u1.z; v[7] = (_Float16)u1.w;
        *(f16x8*)&W_lds[r * 136 + c * 8] = v;
    }
    // stage A tile [128][128]
    if constexpr (IN_F32) {
        const float* A = (const float*)Ain;
        for (int i = tid; i < 2048; i += 256) {
            int r = i >> 4, c = i & 15;
            int gm = m0 + r;
            f16x8 v = {};
            if (gm < n) {
                float4 u0 = *(const float4*)(A + (size_t)gm * 128 + c * 8);
                float4 u1 = *(const float4*)(A + (size_t)gm * 128 + c * 8 + 4);
                v[0] = (_Float16)u0.x; v[1] = (_Float16)u0.y;
                v[2] = (_Float16)u0.z; v[3] = (_Float16)u0.w;
                v[4] = (_Float16)u1.x; v[5] = (_Float16)u1.y;
                v[6] = (_Float16)u1.z; v[7] = (_Float16)u1.w;
            }
            *(f16x8*)&A_lds[r * 136 + c * 8] = v;
        }
    } else {
        const _Float16* A = (const _Float16*)Ain;
        for (int i = tid; i < 2048; i += 256) {
            int r = i >> 4, c = i & 15;
            int gm = m0 + r;
            f16x8 v = {};
            if (gm < n) v = ((const f16x8*)(A + (size_t)gm * 128))[c];
            *(f16x8*)&A_lds[r * 136 + c * 8] = v;
        }
    }
    __syncthreads();

    int m0w = wave * 32;
    int lr  = lane & 15;
    int lk  = (lane >> 4) * 4;

    f32x4 acc[2][NT];
#pragma unroll
    for (int mi = 0; mi < 2; mi++)
#pragma unroll
        for (int ni = 0; ni < NT; ni++) acc[mi][ni] = (f32x4){0.f, 0.f, 0.f, 0.f};

#pragma unroll
    for (int kk = 0; kk < 8; kk++) {
        int k0 = kk * 16;
        f16x4 a0 = *(const f16x4*)&A_lds[(m0w + lr) * 136 + k0 + lk];
        f16x4 a1 = *(const f16x4*)&A_lds[(m0w + 16 + lr) * 136 + k0 + lk];
#pragma unroll
        for (int ni = 0; ni < NT; ni++) {
            f16x4 b = *(const f16x4*)&W_lds[(ni * 16 + lr) * 136 + k0 + lk];
            acc[0][ni] = __builtin_amdgcn_mfma_f32_16x16x16f16(a0, b, acc[0][ni], 0, 0, 0);
            acc[1][ni] = __builtin_amdgcn_mfma_f32_16x16x16f16(a1, b, acc[1][ni], 0, 0, 0);
        }
    }

    int orow = (lane >> 4) * 4;
#pragma unroll
    for (int mi = 0; mi < 2; mi++) {
#pragma unroll
        for (int r = 0; r < 4; r++) {
            int gm = m0 + m0w + mi * 16 + orow + r;
            if (gm < n) {
                _Float16* op = outh + (size_t)gm * KOUT + lr;
#pragma unroll
                for (int ni = 0; ni < NT; ni++)
                    op[ni * 16] = (_Float16)acc[mi][ni][r];
            }
        }
    }
}

// ---------------- aggregation on g: h = act((g[v] + sum_in g[c])*norm + bias) ----------------
// 128-wide fp16 rows: 16 lanes/node, 16 nodes per 256-thread block. Unroll 8.

__global__ __launch_bounds__(256) void k_agg128_br(const _Float16* __restrict__ g,
                                                   const int* __restrict__ offs,
                                                   const int* __restrict__ cols,
                                                   const float* __restrict__ norm,
                                                   const float* __restrict__ bias,
                                                   _Float16* __restrict__ hout, int n) {
    int node = blockIdx.x * 16 + (threadIdx.x >> 4);
    if (node >= n) return;
    int lane = threadIdx.x & 15;

    f16x8 sv = ((const f16x8*)(g + (size_t)node * 128))[lane];
    float acc[8];
#pragma unroll
    for (int j = 0; j < 8; j++) acc[j] = (float)sv[j];

    int p = offs[node], e = offs[node + 1];
    for (; p + 8 <= e; p += 8) {
        int c0 = cols[p],     c1 = cols[p + 1], c2 = cols[p + 2], c3 = cols[p + 3];
        int c4 = cols[p + 4], c5 = cols[p + 5], c6 = cols[p + 6], c7 = cols[p + 7];
        f16x8 a0 = ((const f16x8*)(g + (size_t)c0 * 128))[lane];
        f16x8 a1 = ((const f16x8*)(g + (size_t)c1 * 128))[lane];
        f16x8 a2 = ((const f16x8*)(g + (size_t)c2 * 128))[lane];
        f16x8 a3 = ((const f16x8*)(g + (size_t)c3 * 128))[lane];
        f16x8 a4 = ((const f16x8*)(g + (size_t)c4 * 128))[lane];
        f16x8 a5 = ((const f16x8*)(g + (size_t)c5 * 128))[lane];
        f16x8 a6 = ((const f16x8*)(g + (size_t)c6 * 128))[lane];
        f16x8 a7 = ((const f16x8*)(g + (size_t)c7 * 128))[lane];
#pragma unroll
        for (int j = 0; j < 8; j++)
            acc[j] += (((float)a0[j] + (float)a1[j]) + ((float)a2[j] + (float)a3[j]))
                    + (((float)a4[j] + (float)a5[j]) + ((float)a6[j] + (float)a7[j]));
    }
    for (; p + 4 <= e; p += 4) {
        int c0 = cols[p], c1 = cols[p + 1], c2 = cols[p + 2], c3 = cols[p + 3];
        f16x8 a0 = ((const f16x8*)(g + (size_t)c0 * 128))[lane];
        f16x8 a1 = ((const f16x8*)(g + (size_t)c1 * 128))[lane];
        f16x8 a2 = ((const f16x8*)(g + (size_t)c2 * 128))[lane];
        f16x8 a3 = ((const f16x8*)(g + (size_t)c3 * 128))[lane];
#pragma unroll
        for (int j = 0; j < 8; j++)
            acc[j] += ((float)a0[j] + (float)a1[j]) + ((float)a2[j] + (float)a3[j]);
    }
    for (; p < e; p++) {
        f16x8 a = ((const f16x8*)(g + (size_t)cols[p] * 128))[lane];
#pragma unroll
        for (int j = 0; j < 8; j++) acc[j] += (float)a[j];
    }
    float nm = norm[node];
    float4 bb0 = ((const float4*)bias)[lane * 2];
    float4 bb1 = ((const float4*)bias)[lane * 2 + 1];
    float o[8];
    o[0] = acc[0] * nm + bb0.x; o[1] = acc[1] * nm + bb0.y;
    o[2] = acc[2] * nm + bb0.z; o[3] = acc[3] * nm + bb0.w;
    o[4] = acc[4] * nm + bb1.x; o[5] = acc[5] * nm + bb1.y;
    o[6] = acc[6] * nm + bb1.z; o[7] = acc[7] * nm + bb1.w;
    f16x8 ov;
#pragma unroll
    for (int j = 0; j < 8; j++) ov[j] = (_Float16)fmaxf(o[j], 0.f);
    ((f16x8*)(hout + (size_t)node * 128))[lane] = ov;
}

// 64-wide final: out = (g[v] + sum_in g[c])*norm + bias (fp32 out, no relu)
// 16 lanes/node x f16x4 (8 B), 16 nodes/block. Unroll 8.
__global__ __launch_bounds__(256) void k_agg64_b(const _Float16* __restrict__ g,
                                                 const int* __restrict__ offs,
                                                 const int* __restrict__ cols,
                                                 const float* __restrict__ norm,
                                                 const float* __restrict__ bias,
                                                 float* __restrict__ out, int n) {
    int node = blockIdx.x * 16 + (threadIdx.x >> 4);
    if (node >= n) return;
    int lane = threadIdx.x & 15;

    f16x4 sv = ((const f16x4*)(g + (size_t)node * 64))[lane];
    float acc[4];
#pragma unroll
    for (int j = 0; j < 4; j++) acc[j] = (float)sv[j];

    int p = offs[node], e = offs[node + 1];
    for (; p + 8 <= e; p += 8) {
        int c0 = cols[p],     c1 = cols[p + 1], c2 = cols[p + 2], c3 = cols[p + 3];
        int c4 = cols[p + 4], c5 = cols[p + 5], c6 = cols[p + 6], c7 = cols[p + 7];
        f16x4 a0 = ((const f16x4*)(g + (size_t)c0 * 64))[lane];
        f16x4 a1 = ((const f16x4*)(g + (size_t)c1 * 64))[lane];
        f16x4 a2 = ((const f16x4*)(g + (size_t)c2 * 64))[lane];
        f16x4 a3 = ((const f16x4*)(g + (size_t)c3 * 64))[lane];
        f16x4 a4 = ((const f16x4*)(g + (size_t)c4 * 64))[lane];
        f16x4 a5 = ((const f16x4*)(g + (size_t)c5 * 64))[lane];
        f16x4 a6 = ((const f16x4*)(g + (size_t)c6 * 64))[lane];
        f16x4 a7 = ((const f16x4*)(g + (size_t)c7 * 64))[lane];
#pragma unroll
        for (int j = 0; j < 4; j++)
            acc[j] += (((float)a0[j] + (float)a1[j]) + ((float)a2[j] + (float)a3[j]))
                    + (((float)a4[j] + (float)a5[j]) + ((float)a6[j] + (float)a7[j]));
    }
    for (; p + 4 <= e; p += 4) {
        int c0 = cols[p], c1 = cols[p + 1], c2 = cols[p + 2], c3 = cols[p + 3];
        f16x4 a0 = ((const f16x4*)(g + (size_t)c0 * 64))[lane];
        f16x4 a1 = ((const f16x4*)(g + (size_t)c1 * 64))[lane];
        f16x4 a2 = ((const f16x4*)(g + (size_t)c2 * 64))[lane];
        f16x4 a3 = ((const f16x4*)(g + (size_t)c3 * 64))[lane];
#pragma unroll
        for (int j = 0; j < 4; j++)
            acc[j] += ((float)a0[j] + (float)a1[j]) + ((float)a2[j] + (float)a3[j]);
    }
    for (; p < e; p++) {
        f16x4 a = ((const f16x4*)(g + (size_t)cols[p] * 64))[lane];
#pragma unroll
        for (int j = 0; j < 4; j++) acc[j] += (float)a[j];
    }
    float nm = norm[node];
    float4 bb = ((const float4*)bias)[lane];
    float* op = out + (size_t)node * 64 + lane * 4;
    *(float4*)op = make_float4(acc[0] * nm + bb.x, acc[1] * nm + bb.y,
                               acc[2] * nm + bb.z, acc[3] * nm + bb.w);
}

// ---------------- launch ----------------

extern "C" void kernel_launch(void* const* d_in, const int* in_sizes, int n_in,
                              void* d_out, int out_size, void* d_ws, size_t ws_size,
                              hipStream_t stream) {
    const float* x  = (const float*)d_in[0];
    const int*  src = (const int*)d_in[1];
    const int*  dst = (const int*)d_in[2];
    const float* W1 = (const float*)d_in[3];
    const float* b1 = (const float*)d_in[4];
    const float* W2 = (const float*)d_in[5];
    const float* b2 = (const float*)d_in[6];
    const float* W3 = (const float*)d_in[7];
    const float* b3 = (const float*)d_in[8];
    float* out = (float*)d_out;

    int n = in_sizes[0] / 128;
    int E = in_sizes[1];
    int B = (n + PNODES - 1) >> PSHIFT;
    int total = B * NBLK;
    int chunk = (E + NBLK - 1) / NBLK;
    int G1 = (total + 1023) / 1024;

    char* ws = (char*)d_ws;
    size_t off = 0;
    auto alloc = [&](size_t bytes) -> char* {
        char* p = ws + off;
        off += (bytes + 255) & ~(size_t)255;
        return p;
    };
    int*      bbase   = (int*)alloc(((size_t)B + 1) * 4);
    int*      offsets = (int*)alloc(((size_t)n + 1) * 4);
    float*    norm    = (float*)alloc((size_t)n * 4);
    int*      psum    = (int*)alloc(256 * 4);
    int*      pbase   = (int*)alloc(256 * 4);
    int*      cols    = (int*)alloc((size_t)E * 4);
    _Float16* bufA    = (_Float16*)alloc((size_t)n * 128 * 2);
    _Float16* bufB    = (_Float16*)alloc((size_t)n * 128 * 2);

    // CSR scratch aliases bufA (dead until gemm1 output):
    unsigned int* ebuf  = (unsigned int*)bufA;                           // 6.4 MB
    int*          histT = (int*)((char*)bufA + (size_t)8 * 1024 * 1024); // 400 KB

    // CSR build
    k_hist <<<NBLK, 512, 0, stream>>>(dst, E, chunk, B, histT);
    k_scanA<<<G1, 256, 0, stream>>>(histT, total, psum);
    k_scanB<<<1, 128, 0, stream>>>(psum, G1, pbase, bbase, B, offsets, n, E);
    k_scanC<<<G1, 256, 0, stream>>>(histT, total, pbase, bbase);
    k_place<<<NBLK, 512, 0, stream>>>(src, dst, histT, E, chunk, B, ebuf);
    k_binB <<<B, 256, 0, stream>>>(ebuf, bbase, offsets, norm, cols, n);

    int nblkG = (n + 127) / 128;
    int nblkA = (n + 15) / 16;

    // layer 1 (transform-first): g1 = x @ W1^T ; h1 = relu(agg(g1)*norm + b1)
    k_gemm_mfma<128, true><<<nblkG, 256, 0, stream>>>(x, W1, bufA, n);
    k_agg128_br<<<nblkA, 256, 0, stream>>>(bufA, offsets, cols, norm, b1, bufB, n);
    // layer 2: g2 = h1 @ W2^T ; h2 = relu(agg(g2)*norm + b2)
    k_gemm_mfma<128, false><<<nblkG, 256, 0, stream>>>(bufB, W2, bufA, n);
    k_agg128_br<<<nblkA, 256, 0, stream>>>(bufA, offsets, cols, norm, b2, bufB, n);
    // layer 3: g3 = h2 @ W3^T ; out = agg64(g3)*norm + b3
    k_gemm_mfma<64, false><<<nblkG, 256, 0, stream>>>(bufB, W3, bufA, n);
    k_agg64_b<<<nblkA, 256, 0, stream>>>(bufA, offsets, cols, norm, b3, out, n);
}